// Round 2
// baseline (5795.942 us; speedup 1.0000x reference)
//
#include <hip/hip_runtime.h>
#include <float.h>

#define NPTS  8192
#define FDIM  512
#define NB    2
#define RB    64
#define CB    128
#define KB    32
#define NKT   (FDIM / KB)   // 16
#define TK    12            // candidates kept per row (top-8 + margin)
#define KNN   8

// ---------------- patch extraction: image [2,1,256,256,64] -> feats [2,8192,512]
__global__ void extract_kernel(const float* __restrict__ img, float* __restrict__ feats) {
    int t = blockIdx.x * 256 + threadIdx.x;   // float4 index, 2*8192*128 = 2^21 total
    int fq = t & 127;
    int p  = (t >> 7) & 8191;
    int b  = t >> 20;
    int f = fq << 2;
    int d = f & 7;             // 0 or 4 (8 contiguous in both src and dst)
    int w = (f >> 3) & 7;
    int h = f >> 6;
    int db = p & 7, wb = (p >> 3) & 31, hb = p >> 8;
    size_t src = (((size_t)(b * 256 + hb * 8 + h)) * 256 + (size_t)(wb * 8 + w)) * 64
               + (size_t)(db * 8 + d);
    float4 v = *(const float4*)(img + src);
    *(float4*)(feats + ((size_t)t << 2)) = v;
}

// ---------------- transpose: feats [b][p][f] -> featsT [b][f][p]
__global__ void transpose_kernel(const float* __restrict__ feats, float* __restrict__ featsT) {
    __shared__ float T[64][65];
    int p0 = blockIdx.x * 64;
    int f0 = blockIdx.y * 64;
    int b  = blockIdx.z;
    int tid = threadIdx.x;
    int j4 = tid & 15, i0 = tid >> 4;
#pragma unroll
    for (int pass = 0; pass < 4; ++pass) {
        int i = i0 + pass * 16;
        float4 v = *(const float4*)(feats + ((size_t)(b * NPTS + p0 + i)) * FDIM + f0 + j4 * 4);
        T[i][j4 * 4 + 0] = v.x; T[i][j4 * 4 + 1] = v.y;
        T[i][j4 * 4 + 2] = v.z; T[i][j4 * 4 + 3] = v.w;
    }
    __syncthreads();
    int pi4 = tid & 15, jj0 = tid >> 4;
#pragma unroll
    for (int pass = 0; pass < 4; ++pass) {
        int jj = jj0 + pass * 16;
        float4 v;
        v.x = T[pi4 * 4 + 0][jj]; v.y = T[pi4 * 4 + 1][jj];
        v.z = T[pi4 * 4 + 2][jj]; v.w = T[pi4 * 4 + 3][jj];
        *(float4*)(featsT + ((size_t)(b * FDIM + f0 + jj)) * NPTS + p0 + pi4 * 4) = v;
    }
}

// ---------------- squared norms: one wave per row
__global__ void norms_kernel(const float* __restrict__ feats, float* __restrict__ sq) {
    int gw = blockIdx.x * 4 + (threadIdx.x >> 6);
    int lane = threadIdx.x & 63;
    const float* r = feats + (size_t)gw * FDIM + lane * 8;
    float4 a = *(const float4*)r;
    float4 c = *(const float4*)(r + 4);
    float s = a.x * a.x + a.y * a.y + a.z * a.z + a.w * a.w
            + c.x * c.x + c.y * c.y + c.z * c.z + c.w * c.w;
#pragma unroll
    for (int off = 32; off > 0; off >>= 1) s += __shfl_xor(s, off);
    if (lane == 0) sq[gw] = s;
}

// sorted ascending top-TK insert (fully unrolled, register-resident)
__device__ __forceinline__ void insertTK(float (&td)[TK], int (&ti)[TK], float d, int c) {
#pragma unroll
    for (int p = TK - 1; p > 0; --p) {
        bool bp = d < td[p - 1];
        bool bc = d < td[p];
        float nt = bp ? td[p - 1] : (bc ? d : td[p]);
        int   ni = bp ? ti[p - 1] : (bc ? c : ti[p]);
        td[p] = nt; ti[p] = ni;
    }
    bool b0 = d < td[0];
    td[0] = b0 ? d : td[0];
    ti[0] = b0 ? c : ti[0];
}

// ---------------- candidate kNN: fp32 tiled Gram + running top-12 per row
__global__ __launch_bounds__(256)
void knn_kernel(const float* __restrict__ featsT, const float* __restrict__ sq,
                int* __restrict__ cand) {
    __shared__ float As[KB][RB];    // 8 KB, [k][row]
    __shared__ float Bs[KB][CB];    // 16 KB, [k][col]

    const int b = blockIdx.y;
    const int rowbase = blockIdx.x * RB;
    const float* ftb = featsT + (size_t)b * FDIM * NPTS;
    const float* sqb = sq + b * NPTS;

    const int tid = threadIdx.x;
    const int tx = tid & 15;    // cols tx*8 .. tx*8+7
    const int ty = tid >> 4;    // rows ty*4 .. ty*4+3

    // load index decomposition (A: 2 f4/thread, B: 4 f4/thread per K-chunk)
    const int a_kl0 = tid >> 4;          // + 16*pass
    const int a_r4  = (tid & 15) * 4;
    const int b_kl0 = tid >> 5;          // + 8*pass
    const int b_c4  = (tid & 31) * 4;

    float td[4][TK]; int ti[4][TK];
#pragma unroll
    for (int i = 0; i < 4; ++i)
#pragma unroll
        for (int s = 0; s < TK; ++s) { td[i][s] = FLT_MAX; ti[i][s] = -1; }

    for (int ct = 0; ct < NPTS / CB; ++ct) {
        const int colbase = ct * CB;
        float acc[4][8];
#pragma unroll
        for (int i = 0; i < 4; ++i)
#pragma unroll
            for (int j = 0; j < 8; ++j) acc[i][j] = 0.f;

        float4 pa[2], pb[4];
#pragma unroll
        for (int pass = 0; pass < 2; ++pass)
            pa[pass] = *(const float4*)(ftb + (size_t)(a_kl0 + 16 * pass) * NPTS + rowbase + a_r4);
#pragma unroll
        for (int pass = 0; pass < 4; ++pass)
            pb[pass] = *(const float4*)(ftb + (size_t)(b_kl0 + 8 * pass) * NPTS + colbase + b_c4);

        for (int kt = 0; kt < NKT; ++kt) {
            __syncthreads();   // previous chunk fully consumed
#pragma unroll
            for (int pass = 0; pass < 2; ++pass)
                *(float4*)&As[a_kl0 + 16 * pass][a_r4] = pa[pass];
#pragma unroll
            for (int pass = 0; pass < 4; ++pass)
                *(float4*)&Bs[b_kl0 + 8 * pass][b_c4] = pb[pass];
            __syncthreads();

            if (kt + 1 < NKT) {
                const int kb = (kt + 1) * KB;
#pragma unroll
                for (int pass = 0; pass < 2; ++pass)
                    pa[pass] = *(const float4*)(ftb + (size_t)(kb + a_kl0 + 16 * pass) * NPTS + rowbase + a_r4);
#pragma unroll
                for (int pass = 0; pass < 4; ++pass)
                    pb[pass] = *(const float4*)(ftb + (size_t)(kb + b_kl0 + 8 * pass) * NPTS + colbase + b_c4);
            }

#pragma unroll
            for (int kk = 0; kk < KB; ++kk) {
                float4 av  = *(const float4*)&As[kk][ty * 4];
                float4 bv0 = *(const float4*)&Bs[kk][tx * 8];
                float4 bv1 = *(const float4*)&Bs[kk][tx * 8 + 4];
                float a[4]  = {av.x, av.y, av.z, av.w};
                float bb[8] = {bv0.x, bv0.y, bv0.z, bv0.w, bv1.x, bv1.y, bv1.z, bv1.w};
#pragma unroll
                for (int i = 0; i < 4; ++i)
#pragma unroll
                    for (int j = 0; j < 8; ++j)
                        acc[i][j] = fmaf(a[i], bb[j], acc[i][j]);
            }
        }

        // candidate update: d2 - sq_row = sq_col - 2*dot (monotone in d2)
#pragma unroll
        for (int j = 0; j < 8; ++j) {
            const int c = colbase + tx * 8 + j;
            const float sqc = sqb[c];
#pragma unroll
            for (int i = 0; i < 4; ++i) {
                const int r = rowbase + ty * 4 + i;
                float d = fmaf(-2.f, acc[i][j], sqc);
                if (c == r) d = FLT_MAX;   // exclude self
                if (d < td[i][TK - 1]) insertTK(td[i], ti[i], d, c);
            }
        }
    }

    // in-wave butterfly merge across the 16 tx lanes (same ty group => same wave).
    // SNAPSHOT the partner's list BEFORE inserting: both lanes mutate their lists
    // in lockstep, so interleaved shfl+insert would re-read shifted/duplicated
    // entries (the round-1 bug: duplicate candidates -> multi-counted adjacency).
#pragma unroll
    for (int m = 1; m <= 8; m <<= 1) {
#pragma unroll
        for (int i = 0; i < 4; ++i) {
            float od[TK]; int oi[TK];
#pragma unroll
            for (int s = 0; s < TK; ++s) {
                od[s] = __shfl_xor(td[i][s], m);
                oi[s] = __shfl_xor(ti[i][s], m);
            }
#pragma unroll
            for (int s = 0; s < TK; ++s)
                if (od[s] < td[i][TK - 1]) insertTK(td[i], ti[i], od[s], oi[s]);
        }
    }

    if (tx == 0) {
#pragma unroll
        for (int i = 0; i < 4; ++i) {
            const int r = rowbase + ty * 4 + i;
#pragma unroll
            for (int s = 0; s < TK; ++s)
                cand[((size_t)b * NPTS + r) * TK + s] = ti[i][s];
        }
    }
}

// ---------------- fp64 exact re-rank of 12 candidates + adjacency scatter
__global__ void refine_kernel(const float* __restrict__ feats, const int* __restrict__ cand,
                              float* __restrict__ adj) {
    int gw = blockIdx.x * 4 + (threadIdx.x >> 6);   // 0..16383
    int lane = threadIdx.x & 63;
    int b = gw >> 13;
    int r = gw & (NPTS - 1);
    const float* fb = feats + (size_t)b * NPTS * FDIM;
    const float* fr = fb + (size_t)r * FDIM + lane * 8;
    float* adjb = adj + (size_t)b * NPTS * NPTS;

    float4 a0 = *(const float4*)fr;
    float4 a1 = *(const float4*)(fr + 4);

    double dist[TK];
    int cid[TK];
#pragma unroll
    for (int t = 0; t < TK; ++t) {
        int c = cand[(size_t)gw * TK + t];
        cid[t] = c;
        const float* fc = fb + (size_t)c * FDIM + lane * 8;
        float4 c0 = *(const float4*)fc;
        float4 c1 = *(const float4*)(fc + 4);
        double s = 0.0;
        double e;
        e = (double)a0.x - (double)c0.x; s += e * e;
        e = (double)a0.y - (double)c0.y; s += e * e;
        e = (double)a0.z - (double)c0.z; s += e * e;
        e = (double)a0.w - (double)c0.w; s += e * e;
        e = (double)a1.x - (double)c1.x; s += e * e;
        e = (double)a1.y - (double)c1.y; s += e * e;
        e = (double)a1.z - (double)c1.z; s += e * e;
        e = (double)a1.w - (double)c1.w; s += e * e;
#pragma unroll
        for (int off = 32; off > 0; off >>= 1) s += __shfl_xor(s, off);
        dist[t] = s;   // all lanes hold the full sum
    }

    if (lane < TK) {
        const int t = lane;
        int rank = 0;
        // tie-break by candidate INDEX (matches top_k smallest-index-first)
#pragma unroll
        for (int u = 0; u < TK; ++u)
            rank += (dist[u] < dist[t]) || (dist[u] == dist[t] && cid[u] < cid[t]);
        if (rank < KNN) {
            const int c = cid[t];
            atomicAdd(&adjb[(size_t)r * NPTS + c], 0.5f);
            atomicAdd(&adjb[(size_t)c * NPTS + r], 0.5f);
        }
    }
}

extern "C" void kernel_launch(void* const* d_in, const int* in_sizes, int n_in,
                              void* d_out, int out_size, void* d_ws, size_t ws_size,
                              hipStream_t stream) {
    (void)in_sizes; (void)n_in; (void)out_size; (void)ws_size;
    const float* img = (const float*)d_in[0];

    float* feats = (float*)d_out;                               // 2*8192*512
    float* adj   = feats + (size_t)NB * NPTS * FDIM;            // 2*8192*8192

    float* sqn    = (float*)d_ws;                               // 16384 floats
    int*   cand   = (int*)((char*)d_ws + 65536);                // 16384*TK ints (~786 KB)
    float* featsT = adj;   // stage transposed feats inside adj region (zeroed later)

    extract_kernel  <<<8192, 256, 0, stream>>>(img, feats);
    transpose_kernel<<<dim3(NPTS / 64, FDIM / 64, NB), 256, 0, stream>>>(feats, featsT);
    norms_kernel    <<<(NB * NPTS) / 4, 256, 0, stream>>>(feats, sqn);
    knn_kernel      <<<dim3(NPTS / RB, NB), 256, 0, stream>>>(featsT, sqn, cand);
    hipMemsetAsync(adj, 0, (size_t)NB * NPTS * NPTS * sizeof(float), stream);
    refine_kernel   <<<(NB * NPTS) / 4, 256, 0, stream>>>(feats, cand, adj);
}

// Round 5
// 1203.012 us; speedup vs baseline: 4.8179x; 4.8179x over previous
//
#include <hip/hip_runtime.h>
#include <float.h>

#define NPTS  8192
#define FDIM  512
#define NB    2
#define TK    12
#define KNN   8
#define TK2   24            // candidates per row after merging 2 col-halves

typedef __attribute__((ext_vector_type(8))) short short8;   // 8 bf16 (4 VGPRs)
typedef __attribute__((ext_vector_type(4))) float floatx4;  // MFMA C/D

// ---------------- patch extraction: image [2,1,256,256,64] -> feats [2,8192,512]
__global__ void extract_kernel(const float* __restrict__ img, float* __restrict__ feats) {
    int t = blockIdx.x * 256 + threadIdx.x;
    int fq = t & 127;
    int p  = (t >> 7) & 8191;
    int b  = t >> 20;
    int f = fq << 2;
    int d = f & 7;
    int w = (f >> 3) & 7;
    int h = f >> 6;
    int db = p & 7, wb = (p >> 3) & 31, hb = p >> 8;
    size_t src = (((size_t)(b * 256 + hb * 8 + h)) * 256 + (size_t)(wb * 8 + w)) * 64
               + (size_t)(db * 8 + d);
    float4 v = *(const float4*)(img + src);
    *(float4*)(feats + ((size_t)t << 2)) = v;
}

// ---------------- fp32 -> bf16 (RNE) + scaled squared norms
// score16(r,c) = 16*sq_c - 32*dot + 24576  -> centered ~32768, range ~[26k, 40k]
__device__ __forceinline__ unsigned f2bf(float x) {
    unsigned u = __float_as_uint(x);
    return (u + 0x7FFFu + ((u >> 16) & 1u)) >> 16;
}

__global__ void prep_kernel(const float* __restrict__ feats, ushort* __restrict__ bf,
                            float* __restrict__ sqc16) {
    int gw = blockIdx.x * 4 + (threadIdx.x >> 6);   // row 0..16383
    int lane = threadIdx.x & 63;
    const float* r = feats + (size_t)gw * FDIM + lane * 8;
    float4 a = *(const float4*)r;
    float4 c = *(const float4*)(r + 4);
    uint4 wv;
    wv.x = f2bf(a.x) | (f2bf(a.y) << 16);
    wv.y = f2bf(a.z) | (f2bf(a.w) << 16);
    wv.z = f2bf(c.x) | (f2bf(c.y) << 16);
    wv.w = f2bf(c.z) | (f2bf(c.w) << 16);
    *(uint4*)(bf + (size_t)gw * FDIM + lane * 8) = wv;
    float s = a.x * a.x + a.y * a.y + a.z * a.z + a.w * a.w
            + c.x * c.x + c.y * c.y + c.z * c.z + c.w * c.w;
#pragma unroll
    for (int off = 32; off > 0; off >>= 1) s += __shfl_xor(s, off);
    if (lane == 0) sqc16[gw] = s * 16.f + 24576.f;   // was -8192: clamped half the scores!
}

// packed-key sorted top-12 insert (key = d16<<16 | col  -> ties pick smaller col)
__device__ __forceinline__ void insert12(unsigned* L, unsigned key) {
#pragma unroll
    for (int p = TK - 1; p > 0; --p) {
        bool bp = key < L[p - 1];
        bool bc = key < L[p];
        L[p] = bp ? L[p - 1] : (bc ? key : L[p]);
    }
    L[0] = (key < L[0]) ? key : L[0];
}

__device__ __forceinline__ int swz(int x) { return (x & 3) ^ ((x >> 2) & 3); }

__device__ __forceinline__ void gl_lds16(const ushort* g, ushort* l) {
    __builtin_amdgcn_global_load_lds(
        (const __attribute__((address_space(1))) unsigned int*)g,
        (__attribute__((address_space(3))) unsigned int*)l, 16, 0, 0);
}

// ---------------- MFMA bf16 Gram + u16 fixed-point score + top-12 per row-half
// grid (64 rowblocks, NB, 2 col-halves), 256 threads. Block: rows 128, cols 4096.
__global__ __launch_bounds__(256, 1)
void knn_mfma(const ushort* __restrict__ bfeats, const float* __restrict__ sqc16,
              ushort* __restrict__ cand) {
    __shared__ __align__(16) ushort As[128 * 32];    // 8 KB  [row][32k] swizzled 16B groups
    __shared__ __align__(16) ushort Bs[256 * 32];    // 16 KB [col][32k] swizzled
    __shared__ __align__(16) ushort Sc[64 * 264];    // 33.8 KB scores, stride 264

    const int row0 = blockIdx.x * 128;
    const int b    = blockIdx.y;
    const int half = blockIdx.z;
    const ushort* bfb = bfeats + (size_t)b * NPTS * FDIM;
    const float*  sqg = sqc16 + b * NPTS;

    const int tid  = threadIdx.x;
    const int wid  = tid >> 6;
    const int lane = tid & 63;
    const int l15  = lane & 15;
    const int q    = lane >> 4;
    const int wr   = wid & 1;    // row 64-half of the wave
    const int wc   = wid >> 1;   // col 128-half of the wave

    // kstep-invariant fragment LDS offsets (ushort units); uniform-bank by swizzle
    const int fsw = (q ^ swz(l15)) << 3;
    int aoff[4], boff[8];
#pragma unroll
    for (int rf = 0; rf < 4; ++rf) aoff[rf] = ((wr * 64 + rf * 16 + l15) << 5) + fsw;
#pragma unroll
    for (int cf = 0; cf < 8; ++cf) boff[cf] = ((wc * 128 + cf * 16 + l15) << 5) + fsw;

    // staging decomposition: 4 lanes per 64B row-chunk, group XOR-swizzled
    const int srl = lane >> 2;                    // row/col within 16-group
    const int sg  = (lane & 3) ^ swz(srl);        // global 16B group to fetch

    unsigned L[2][TK];
#pragma unroll
    for (int h = 0; h < 2; ++h)
#pragma unroll
        for (int s = 0; s < TK; ++s) L[h][s] = 0xFFFFFFFFu;

    const int srow = tid >> 2;      // selection: 4 threads per score-row
    const int scp  = tid & 3;       // each scans 64 cols

    for (int ct = 0; ct < 16; ++ct) {
        const int colb = half * 4096 + ct * 256;

        float sqv[8];
#pragma unroll
        for (int cf = 0; cf < 8; ++cf) sqv[cf] = sqg[colb + wc * 128 + cf * 16 + l15];

        floatx4 acc[4][8];
#pragma unroll
        for (int rf = 0; rf < 4; ++rf)
#pragma unroll
            for (int cf = 0; cf < 8; ++cf) acc[rf][cf] = (floatx4)0.f;

        for (int kt = 0; kt < 16; ++kt) {
            const int kb = kt * 32;
            __syncthreads();
            // stage A: 8 wave-instructions (2/wave), 16 rows each
#pragma unroll
            for (int p = 0; p < 2; ++p) {
                int rg = wid * 2 + p;
                gl_lds16(bfb + (size_t)(row0 + rg * 16 + srl) * FDIM + kb + sg * 8,
                         &As[rg * 512]);
            }
            // stage B: 16 wave-instructions (4/wave)
#pragma unroll
            for (int p = 0; p < 4; ++p) {
                int cg = wid * 4 + p;
                gl_lds16(bfb + (size_t)(colb + cg * 16 + srl) * FDIM + kb + sg * 8,
                         &Bs[cg * 512]);
            }
            __syncthreads();

            short8 av[4], bv[8];
#pragma unroll
            for (int rf = 0; rf < 4; ++rf) av[rf] = *(const short8*)&As[aoff[rf]];
#pragma unroll
            for (int cf = 0; cf < 8; ++cf) bv[cf] = *(const short8*)&Bs[boff[cf]];
#pragma unroll
            for (int rf = 0; rf < 4; ++rf)
#pragma unroll
                for (int cf = 0; cf < 8; ++cf)
                    acc[rf][cf] = __builtin_amdgcn_mfma_f32_16x16x32_bf16(
                        av[rf], bv[cf], acc[rf][cf], 0, 0, 0);
        }

        // epilogue: two 64-row phases (Sc buffer holds 64 rows)
#pragma unroll
        for (int hr = 0; hr < 2; ++hr) {
            __syncthreads();
            if (wr == hr) {
#pragma unroll
                for (int rf = 0; rf < 4; ++rf)
#pragma unroll
                    for (int cf = 0; cf < 8; ++cf) {
                        const int ctl = wc * 128 + cf * 16 + l15;
                        const int gcol = colb + ctl;
#pragma unroll
                        for (int v = 0; v < 4; ++v) {
                            const int rbuf = rf * 16 + q * 4 + v;
                            const int grow = row0 + hr * 64 + rbuf;
                            float s = fmaf(-32.f, acc[rf][cf][v], sqv[cf]);
                            s = fminf(fmaxf(s, 0.f), 65535.f);
                            ushort us = (grow == gcol) ? (ushort)65535 : (ushort)s;
                            Sc[rbuf * 264 + ctl] = us;
                        }
                    }
            }
            __syncthreads();
            // selection: thread scans 64 cols of its row
            const ushort* base = &Sc[srow * 264 + scp * 64];
            const int colg0 = colb + scp * 64;
            unsigned* Lp = L[hr];
#pragma unroll
            for (int j = 0; j < 8; ++j) {
                uint4 w = *(const uint4*)(base + j * 8);
                const int c0 = colg0 + j * 8;
                unsigned k;
                k = (w.x << 16) | (unsigned)(c0 + 0); if (k < Lp[TK-1]) insert12(Lp, k);
                k = (w.x & 0xFFFF0000u) | (unsigned)(c0 + 1); if (k < Lp[TK-1]) insert12(Lp, k);
                k = (w.y << 16) | (unsigned)(c0 + 2); if (k < Lp[TK-1]) insert12(Lp, k);
                k = (w.y & 0xFFFF0000u) | (unsigned)(c0 + 3); if (k < Lp[TK-1]) insert12(Lp, k);
                k = (w.z << 16) | (unsigned)(c0 + 4); if (k < Lp[TK-1]) insert12(Lp, k);
                k = (w.z & 0xFFFF0000u) | (unsigned)(c0 + 5); if (k < Lp[TK-1]) insert12(Lp, k);
                k = (w.w << 16) | (unsigned)(c0 + 6); if (k < Lp[TK-1]) insert12(Lp, k);
                k = (w.w & 0xFFFF0000u) | (unsigned)(c0 + 7); if (k < Lp[TK-1]) insert12(Lp, k);
            }
        }
    }

    // merge the 4 scanners of each row (butterfly, snapshot-then-insert)
#pragma unroll
    for (int m = 1; m <= 2; m <<= 1) {
#pragma unroll
        for (int h = 0; h < 2; ++h) {
            unsigned o[TK];
#pragma unroll
            for (int s = 0; s < TK; ++s) o[s] = (unsigned)__shfl_xor((int)L[h][s], m);
#pragma unroll
            for (int s = 0; s < TK; ++s)
                if (o[s] < L[h][TK - 1]) insert12(L[h], o[s]);
        }
    }

    if (scp == 0) {
#pragma unroll
        for (int h = 0; h < 2; ++h) {
            const int grow = row0 + h * 64 + srow;
            ushort* dst = cand + ((size_t)(b * 2 + half) * NPTS + grow) * TK;
#pragma unroll
            for (int s = 0; s < TK; ++s) dst[s] = (ushort)(L[h][s] & 0xFFFFu);
        }
    }
}

// ---------------- fp64 exact re-rank of 24 candidates + adjacency scatter
__global__ void refine_kernel(const float* __restrict__ feats, const ushort* __restrict__ cand,
                              float* __restrict__ adj) {
    int gw = blockIdx.x * 4 + (threadIdx.x >> 6);   // 0..16383
    int lane = threadIdx.x & 63;
    int b = gw >> 13;
    int r = gw & (NPTS - 1);
    const float* fb = feats + (size_t)b * NPTS * FDIM;
    const float* fr = fb + (size_t)r * FDIM + lane * 8;
    float* adjb = adj + (size_t)b * NPTS * NPTS;

    float4 a0 = *(const float4*)fr;
    float4 a1 = *(const float4*)(fr + 4);

    double dist[TK2];
    int cid[TK2];
#pragma unroll
    for (int t = 0; t < TK2; ++t) {
        int hf = t / TK, s = t % TK;
        int c = cand[((size_t)(b * 2 + hf) * NPTS + r) * TK + s] & (NPTS - 1);
        cid[t] = c;
        const float* fc = fb + (size_t)c * FDIM + lane * 8;
        float4 c0 = *(const float4*)fc;
        float4 c1 = *(const float4*)(fc + 4);
        double sm = 0.0, e;
        e = (double)a0.x - (double)c0.x; sm += e * e;
        e = (double)a0.y - (double)c0.y; sm += e * e;
        e = (double)a0.z - (double)c0.z; sm += e * e;
        e = (double)a0.w - (double)c0.w; sm += e * e;
        e = (double)a1.x - (double)c1.x; sm += e * e;
        e = (double)a1.y - (double)c1.y; sm += e * e;
        e = (double)a1.z - (double)c1.z; sm += e * e;
        e = (double)a1.w - (double)c1.w; sm += e * e;
#pragma unroll
        for (int off = 32; off > 0; off >>= 1) sm += __shfl_xor(sm, off);
        dist[t] = sm;
    }

    if (lane < TK2) {
        const int t = lane;
        int rank = 0;
#pragma unroll
        for (int u = 0; u < TK2; ++u)
            rank += (dist[u] < dist[t]) || (dist[u] == dist[t] && cid[u] < cid[t]);
        if (rank < KNN) {
            const int c = cid[t];
            atomicAdd(&adjb[(size_t)r * NPTS + c], 0.5f);
            atomicAdd(&adjb[(size_t)c * NPTS + r], 0.5f);
        }
    }
}

extern "C" void kernel_launch(void* const* d_in, const int* in_sizes, int n_in,
                              void* d_out, int out_size, void* d_ws, size_t ws_size,
                              hipStream_t stream) {
    (void)in_sizes; (void)n_in; (void)out_size; (void)ws_size;
    const float* img = (const float*)d_in[0];

    float* feats = (float*)d_out;                               // 2*8192*512
    float* adj   = feats + (size_t)NB * NPTS * FDIM;            // 2*8192*8192

    float*  sqc16 = (float*)d_ws;                               // 16384 floats
    ushort* cand  = (ushort*)((char*)d_ws + 65536);             // 16384*24 ushorts (786 KB)
    ushort* bfeat = (ushort*)adj;   // bf16 feats staged in adj region (wiped by memset later)

    extract_kernel<<<8192, 256, 0, stream>>>(img, feats);
    prep_kernel   <<<(NB * NPTS) / 4, 256, 0, stream>>>(feats, bfeat, sqc16);
    knn_mfma      <<<dim3(NPTS / 128, NB, 2), 256, 0, stream>>>(bfeat, sqc16, cand);
    (void)hipMemsetAsync(adj, 0, (size_t)NB * NPTS * NPTS * sizeof(float), stream);
    refine_kernel <<<(NB * NPTS) / 4, 256, 0, stream>>>(feats, cand, adj);
}

// Round 6
// 954.833 us; speedup vs baseline: 6.0701x; 1.2599x over previous
//
#include <hip/hip_runtime.h>
#include <float.h>

#define NPTS  8192
#define FDIM  512
#define NB    2
#define TK    12
#define KNN   8
#define NQ    4             // column quarters

typedef __attribute__((ext_vector_type(8))) short short8;   // 8 bf16 (4 VGPRs)
typedef __attribute__((ext_vector_type(4))) float floatx4;  // MFMA C/D

// ---------------- patch extraction: image [2,1,256,256,64] -> feats [2,8192,512]
__global__ void extract_kernel(const float* __restrict__ img, float* __restrict__ feats) {
    int t = blockIdx.x * 256 + threadIdx.x;
    int fq = t & 127;
    int p  = (t >> 7) & 8191;
    int b  = t >> 20;
    int f = fq << 2;
    int d = f & 7;
    int w = (f >> 3) & 7;
    int h = f >> 6;
    int db = p & 7, wb = (p >> 3) & 31, hb = p >> 8;
    size_t src = (((size_t)(b * 256 + hb * 8 + h)) * 256 + (size_t)(wb * 8 + w)) * 64
               + (size_t)(db * 8 + d);
    float4 v = *(const float4*)(img + src);
    *(float4*)(feats + ((size_t)t << 2)) = v;
}

// ---------------- fp32 -> bf16 (RNE) + scaled squared norms
// score16(r,c) = 16*sq_c - 32*dot + 24576  -> centered ~32768, range ~[26k, 40k]
__device__ __forceinline__ unsigned f2bf(float x) {
    unsigned u = __float_as_uint(x);
    return (u + 0x7FFFu + ((u >> 16) & 1u)) >> 16;
}

__global__ void prep_kernel(const float* __restrict__ feats, ushort* __restrict__ bf,
                            float* __restrict__ sqc16) {
    int gw = blockIdx.x * 4 + (threadIdx.x >> 6);   // row 0..16383
    int lane = threadIdx.x & 63;
    const float* r = feats + (size_t)gw * FDIM + lane * 8;
    float4 a = *(const float4*)r;
    float4 c = *(const float4*)(r + 4);
    uint4 wv;
    wv.x = f2bf(a.x) | (f2bf(a.y) << 16);
    wv.y = f2bf(a.z) | (f2bf(a.w) << 16);
    wv.z = f2bf(c.x) | (f2bf(c.y) << 16);
    wv.w = f2bf(c.z) | (f2bf(c.w) << 16);
    *(uint4*)(bf + (size_t)gw * FDIM + lane * 8) = wv;
    float s = a.x * a.x + a.y * a.y + a.z * a.z + a.w * a.w
            + c.x * c.x + c.y * c.y + c.z * c.z + c.w * c.w;
#pragma unroll
    for (int off = 32; off > 0; off >>= 1) s += __shfl_xor(s, off);
    if (lane == 0) sqc16[gw] = s * 16.f + 24576.f;
}

// packed-key sorted top-12 insert (key = d16<<16 | col  -> ties pick smaller col)
__device__ __forceinline__ void insert12(unsigned* L, unsigned key) {
#pragma unroll
    for (int p = TK - 1; p > 0; --p) {
        bool bp = key < L[p - 1];
        bool bc = key < L[p];
        L[p] = bp ? L[p - 1] : (bc ? key : L[p]);
    }
    L[0] = (key < L[0]) ? key : L[0];
}

__device__ __forceinline__ int swz(int x) { return (x & 3) ^ ((x >> 2) & 3); }

__device__ __forceinline__ void gl_lds16(const ushort* g, ushort* l) {
    __builtin_amdgcn_global_load_lds(
        (const __attribute__((address_space(1))) unsigned int*)g,
        (__attribute__((address_space(3))) unsigned int*)l, 16, 0, 0);
}

// ---------------- MFMA bf16 Gram + u16 fixed-point score + top-12 per quarter
// grid (64 rowblocks, NB, 4 col-quarters), 256 threads. Block: rows 128, cols 2048.
// 512 blocks -> 2 blocks/CU: one block's MFMA hides the other's barrier drain.
__global__ __launch_bounds__(256, 2)
void knn_mfma(const ushort* __restrict__ bfeats, const float* __restrict__ sqc16,
              unsigned* __restrict__ cand) {
    __shared__ __align__(16) ushort As[128 * 32];    // 8 KB  [row][32k] swizzled 16B groups
    __shared__ __align__(16) ushort Bs[256 * 32];    // 16 KB [col][32k] swizzled
    __shared__ __align__(16) ushort Sc[64 * 264];    // 33.8 KB scores, stride 264

    const int row0 = blockIdx.x * 128;
    const int b    = blockIdx.y;
    const int quarter = blockIdx.z;
    const ushort* bfb = bfeats + (size_t)b * NPTS * FDIM;
    const float*  sqg = sqc16 + b * NPTS;

    const int tid  = threadIdx.x;
    const int wid  = tid >> 6;
    const int lane = tid & 63;
    const int l15  = lane & 15;
    const int q    = lane >> 4;
    const int wr   = wid & 1;    // row 64-half of the wave
    const int wc   = wid >> 1;   // col 128-half of the wave

    // kstep-invariant fragment LDS offsets (ushort units); uniform-bank by swizzle
    const int fsw = (q ^ swz(l15)) << 3;
    int aoff[4], boff[8];
#pragma unroll
    for (int rf = 0; rf < 4; ++rf) aoff[rf] = ((wr * 64 + rf * 16 + l15) << 5) + fsw;
#pragma unroll
    for (int cf = 0; cf < 8; ++cf) boff[cf] = ((wc * 128 + cf * 16 + l15) << 5) + fsw;

    // staging decomposition: 4 lanes per 64B row-chunk, group XOR-swizzled
    const int srl = lane >> 2;                    // row/col within 16-group
    const int sg  = (lane & 3) ^ swz(srl);        // global 16B group to fetch

    unsigned L[2][TK];
#pragma unroll
    for (int h = 0; h < 2; ++h)
#pragma unroll
        for (int s = 0; s < TK; ++s) L[h][s] = 0xFFFFFFFFu;

    const int srow = tid >> 2;      // selection: 4 threads per score-row
    const int scp  = tid & 3;       // each scans 64 cols

    for (int ct = 0; ct < 8; ++ct) {
        const int colb = quarter * 2048 + ct * 256;

        float sqv[8];
#pragma unroll
        for (int cf = 0; cf < 8; ++cf) sqv[cf] = sqg[colb + wc * 128 + cf * 16 + l15];

        floatx4 acc[4][8];
#pragma unroll
        for (int rf = 0; rf < 4; ++rf)
#pragma unroll
            for (int cf = 0; cf < 8; ++cf) acc[rf][cf] = (floatx4)0.f;

        for (int kt = 0; kt < 16; ++kt) {
            const int kb = kt * 32;
            __syncthreads();
#pragma unroll
            for (int p = 0; p < 2; ++p) {
                int rg = wid * 2 + p;
                gl_lds16(bfb + (size_t)(row0 + rg * 16 + srl) * FDIM + kb + sg * 8,
                         &As[rg * 512]);
            }
#pragma unroll
            for (int p = 0; p < 4; ++p) {
                int cg = wid * 4 + p;
                gl_lds16(bfb + (size_t)(colb + cg * 16 + srl) * FDIM + kb + sg * 8,
                         &Bs[cg * 512]);
            }
            __syncthreads();

            short8 av[4], bv[8];
#pragma unroll
            for (int rf = 0; rf < 4; ++rf) av[rf] = *(const short8*)&As[aoff[rf]];
#pragma unroll
            for (int cf = 0; cf < 8; ++cf) bv[cf] = *(const short8*)&Bs[boff[cf]];
#pragma unroll
            for (int rf = 0; rf < 4; ++rf)
#pragma unroll
                for (int cf = 0; cf < 8; ++cf)
                    acc[rf][cf] = __builtin_amdgcn_mfma_f32_16x16x32_bf16(
                        av[rf], bv[cf], acc[rf][cf], 0, 0, 0);
        }

        // epilogue: two 64-row phases (Sc buffer holds 64 rows)
#pragma unroll
        for (int hr = 0; hr < 2; ++hr) {
            __syncthreads();
            if (wr == hr) {
#pragma unroll
                for (int rf = 0; rf < 4; ++rf)
#pragma unroll
                    for (int cf = 0; cf < 8; ++cf) {
                        const int ctl = wc * 128 + cf * 16 + l15;
                        const int gcol = colb + ctl;
#pragma unroll
                        for (int v = 0; v < 4; ++v) {
                            const int rbuf = rf * 16 + q * 4 + v;
                            const int grow = row0 + hr * 64 + rbuf;
                            float s = fmaf(-32.f, acc[rf][cf][v], sqv[cf]);
                            s = fminf(fmaxf(s, 0.f), 65535.f);
                            ushort us = (grow == gcol) ? (ushort)65535 : (ushort)s;
                            Sc[rbuf * 264 + ctl] = us;
                        }
                    }
            }
            __syncthreads();
            const ushort* base = &Sc[srow * 264 + scp * 64];
            const int colg0 = colb + scp * 64;
            unsigned* Lp = L[hr];
#pragma unroll
            for (int j = 0; j < 8; ++j) {
                uint4 w = *(const uint4*)(base + j * 8);
                const int c0 = colg0 + j * 8;
                unsigned k;
                k = (w.x << 16) | (unsigned)(c0 + 0); if (k < Lp[TK-1]) insert12(Lp, k);
                k = (w.x & 0xFFFF0000u) | (unsigned)(c0 + 1); if (k < Lp[TK-1]) insert12(Lp, k);
                k = (w.y << 16) | (unsigned)(c0 + 2); if (k < Lp[TK-1]) insert12(Lp, k);
                k = (w.y & 0xFFFF0000u) | (unsigned)(c0 + 3); if (k < Lp[TK-1]) insert12(Lp, k);
                k = (w.z << 16) | (unsigned)(c0 + 4); if (k < Lp[TK-1]) insert12(Lp, k);
                k = (w.z & 0xFFFF0000u) | (unsigned)(c0 + 5); if (k < Lp[TK-1]) insert12(Lp, k);
                k = (w.w << 16) | (unsigned)(c0 + 6); if (k < Lp[TK-1]) insert12(Lp, k);
                k = (w.w & 0xFFFF0000u) | (unsigned)(c0 + 7); if (k < Lp[TK-1]) insert12(Lp, k);
            }
        }
    }

    // merge the 4 scanners of each row (butterfly, snapshot-then-insert)
#pragma unroll
    for (int m = 1; m <= 2; m <<= 1) {
#pragma unroll
        for (int h = 0; h < 2; ++h) {
            unsigned o[TK];
#pragma unroll
            for (int s = 0; s < TK; ++s) o[s] = (unsigned)__shfl_xor((int)L[h][s], m);
#pragma unroll
            for (int s = 0; s < TK; ++s)
                if (o[s] < L[h][TK - 1]) insert12(L[h], o[s]);
        }
    }

    if (scp == 0) {
#pragma unroll
        for (int h = 0; h < 2; ++h) {
            const int grow = row0 + h * 64 + srow;
            unsigned* dst = cand + ((size_t)(b * NQ + quarter) * NPTS + grow) * TK;
#pragma unroll
            for (int s = 0; s < TK; ++s) dst[s] = L[h][s];   // full 32-bit keys
        }
    }
}

// ---------------- merge 4x12 keys -> top-12, fp64 exact re-rank, adjacency scatter
__global__ void refine_kernel(const float* __restrict__ feats, const unsigned* __restrict__ cand,
                              float* __restrict__ adj) {
    __shared__ unsigned scols[4][TK];
    const int wv   = threadIdx.x >> 6;
    const int lane = threadIdx.x & 63;
    const int gw = blockIdx.x * 4 + wv;             // 0..16383
    const int b = gw >> 13;
    const int r = gw & (NPTS - 1);

    // load the 4 quarter-lists (48 keys; scores globally comparable, cols unique)
    unsigned key = 0xFFFFFFFFu;
    if (lane < NQ * TK) {
        int qf = lane / TK, s = lane % TK;
        key = cand[((size_t)(b * NQ + qf) * NPTS + r) * TK + s];
    }
    // rank of this key among all 48 (strict less; keys are unique)
    int rank = 0;
#pragma unroll
    for (int u = 0; u < NQ * TK; ++u) {
        unsigned ku = (unsigned)__shfl((int)key, u);
        rank += (ku < key) ? 1 : 0;
    }
    if (lane < NQ * TK && rank < TK) scols[wv][rank] = key & 0xFFFFu;
    __syncthreads();

    const float* fb = feats + (size_t)b * NPTS * FDIM;
    const float* fr = fb + (size_t)r * FDIM + lane * 8;
    float* adjb = adj + (size_t)b * NPTS * NPTS;

    float4 a0 = *(const float4*)fr;
    float4 a1 = *(const float4*)(fr + 4);

    double dist[TK];
#pragma unroll
    for (int t = 0; t < TK; ++t) {
        int c = (int)scols[wv][t];
        const float* fc = fb + (size_t)c * FDIM + lane * 8;
        float4 c0 = *(const float4*)fc;
        float4 c1 = *(const float4*)(fc + 4);
        double sm = 0.0, e;
        e = (double)a0.x - (double)c0.x; sm += e * e;
        e = (double)a0.y - (double)c0.y; sm += e * e;
        e = (double)a0.z - (double)c0.z; sm += e * e;
        e = (double)a0.w - (double)c0.w; sm += e * e;
        e = (double)a1.x - (double)c1.x; sm += e * e;
        e = (double)a1.y - (double)c1.y; sm += e * e;
        e = (double)a1.z - (double)c1.z; sm += e * e;
        e = (double)a1.w - (double)c1.w; sm += e * e;
#pragma unroll
        for (int off = 32; off > 0; off >>= 1) sm += __shfl_xor(sm, off);
        dist[t] = sm;
    }

    if (lane < TK) {
        const int t = lane;
        const int ct = (int)scols[wv][t];
        int rk = 0;
#pragma unroll
        for (int u = 0; u < TK; ++u) {
            int cu = (int)scols[wv][u];
            rk += (dist[u] < dist[t]) || (dist[u] == dist[t] && cu < ct);
        }
        if (rk < KNN) {
            atomicAdd(&adjb[(size_t)r * NPTS + ct], 0.5f);
            atomicAdd(&adjb[(size_t)ct * NPTS + r], 0.5f);
        }
    }
}

extern "C" void kernel_launch(void* const* d_in, const int* in_sizes, int n_in,
                              void* d_out, int out_size, void* d_ws, size_t ws_size,
                              hipStream_t stream) {
    (void)in_sizes; (void)n_in; (void)out_size; (void)ws_size;
    const float* img = (const float*)d_in[0];

    float* feats = (float*)d_out;                               // 2*8192*512
    float* adj   = feats + (size_t)NB * NPTS * FDIM;            // 2*8192*8192

    float*    sqc16 = (float*)d_ws;                             // 16384 floats
    unsigned* cand  = (unsigned*)((char*)d_ws + 65536);         // 16384*4*12 u32 (~3.1 MB)
    ushort*   bfeat = (ushort*)adj;  // bf16 feats staged in adj region (wiped by memset later)

    extract_kernel<<<8192, 256, 0, stream>>>(img, feats);
    prep_kernel   <<<(NB * NPTS) / 4, 256, 0, stream>>>(feats, bfeat, sqc16);
    knn_mfma      <<<dim3(NPTS / 128, NB, NQ), 256, 0, stream>>>(bfeat, sqc16, cand);
    (void)hipMemsetAsync(adj, 0, (size_t)NB * NPTS * NPTS * sizeof(float), stream);
    refine_kernel <<<(NB * NPTS) / 4, 256, 0, stream>>>(feats, cand, adj);
}

// Round 7
// 954.609 us; speedup vs baseline: 6.0715x; 1.0002x over previous
//
#include <hip/hip_runtime.h>
#include <float.h>

#define NPTS  8192
#define FDIM  512
#define NB    2
#define TK    12
#define KNN   8
#define NQ    4             // column quarters

typedef __attribute__((ext_vector_type(8))) short short8;   // 8 bf16 (4 VGPRs)
typedef __attribute__((ext_vector_type(4))) float floatx4;  // MFMA C/D

// ---------------- fp32 -> bf16 (RNE)
__device__ __forceinline__ unsigned f2bf(float x) {
    unsigned u = __float_as_uint(x);
    return (u + 0x7FFFu + ((u >> 16) & 1u)) >> 16;
}

// ---------------- fused: patch extraction + bf16 cast + scaled norms
// image [2,1,256,256,64] -> feats [2,8192,512] (fp32), bfeat (bf16), sqc16
// score16(r,c) = 16*sq_c - 32*dot + 24576 -> centered ~32768
__global__ void extract_prep_kernel(const float* __restrict__ img, float* __restrict__ feats,
                                    ushort* __restrict__ bf, float* __restrict__ sqc16) {
    __shared__ float part[4];
    const int tid = threadIdx.x;
    int t = blockIdx.x * 256 + tid;   // float4 index; block covers 2 rows (128 f4 each)
    int fq = t & 127;
    int p  = (t >> 7) & 8191;
    int b  = t >> 20;
    int f = fq << 2;
    int d = f & 7;
    int w = (f >> 3) & 7;
    int h = f >> 6;
    int db = p & 7, wb = (p >> 3) & 31, hb = p >> 8;
    size_t src = (((size_t)(b * 256 + hb * 8 + h)) * 256 + (size_t)(wb * 8 + w)) * 64
               + (size_t)(db * 8 + d);
    float4 v = *(const float4*)(img + src);
    *(float4*)(feats + ((size_t)t << 2)) = v;
    uint2 wv;
    wv.x = f2bf(v.x) | (f2bf(v.y) << 16);
    wv.y = f2bf(v.z) | (f2bf(v.w) << 16);
    *(uint2*)(bf + ((size_t)t << 2)) = wv;
    float s = v.x * v.x + v.y * v.y + v.z * v.z + v.w * v.w;
#pragma unroll
    for (int off = 32; off > 0; off >>= 1) s += __shfl_xor(s, off);
    if ((tid & 63) == 0) part[tid >> 6] = s;
    __syncthreads();
    if (tid < 2) {
        int gw = blockIdx.x * 2 + tid;   // flat row 0..16383
        sqc16[gw] = (part[2 * tid] + part[2 * tid + 1]) * 16.f + 24576.f;
    }
}

// packed-key sorted top-12 insert (key = d16<<16 | col  -> ties pick smaller col)
__device__ __forceinline__ void insert12(unsigned* L, unsigned key) {
#pragma unroll
    for (int p = TK - 1; p > 0; --p) {
        bool bp = key < L[p - 1];
        bool bc = key < L[p];
        L[p] = bp ? L[p - 1] : (bc ? key : L[p]);
    }
    L[0] = (key < L[0]) ? key : L[0];
}

__device__ __forceinline__ int swz(int x) { return (x & 3) ^ ((x >> 2) & 3); }

__device__ __forceinline__ unsigned pkminu16(unsigned a, unsigned b) {
    unsigned d;
    asm("v_pk_min_u16 %0, %1, %2" : "=v"(d) : "v"(a), "v"(b));
    return d;
}

__device__ __forceinline__ void gl_lds16(const ushort* g, ushort* l) {
    __builtin_amdgcn_global_load_lds(
        (const __attribute__((address_space(1))) unsigned int*)g,
        (__attribute__((address_space(3))) unsigned int*)l, 16, 0, 0);
}

// ---------------- MFMA bf16 Gram + u16 fixed-point score + top-12 per quarter
// grid (64 rowblocks, NB, 4 col-quarters), 256 threads. Block: rows 128, cols 2048.
// 512 blocks -> 2 blocks/CU: one block's MFMA hides the other's barrier drain.
__global__ __launch_bounds__(256, 2)
void knn_mfma(const ushort* __restrict__ bfeats, const float* __restrict__ sqc16,
              unsigned* __restrict__ cand) {
    __shared__ __align__(16) ushort As[128 * 32];    // 8 KB  [row][32k] swizzled 16B groups
    __shared__ __align__(16) ushort Bs[256 * 32];    // 16 KB [col][32k] swizzled
    __shared__ __align__(16) ushort Sc[64 * 264];    // 33.8 KB scores, stride 264

    const int row0 = blockIdx.x * 128;
    const int b    = blockIdx.y;
    const int quarter = blockIdx.z;
    const ushort* bfb = bfeats + (size_t)b * NPTS * FDIM;
    const float*  sqg = sqc16 + b * NPTS;

    const int tid  = threadIdx.x;
    const int wid  = tid >> 6;
    const int lane = tid & 63;
    const int l15  = lane & 15;
    const int q    = lane >> 4;
    const int wr   = wid & 1;    // row 64-half of the wave
    const int wc   = wid >> 1;   // col 128-half of the wave

    // kstep-invariant fragment LDS offsets (ushort units); uniform-bank by swizzle
    const int fsw = (q ^ swz(l15)) << 3;
    int aoff[4], boff[8];
#pragma unroll
    for (int rf = 0; rf < 4; ++rf) aoff[rf] = ((wr * 64 + rf * 16 + l15) << 5) + fsw;
#pragma unroll
    for (int cf = 0; cf < 8; ++cf) boff[cf] = ((wc * 128 + cf * 16 + l15) << 5) + fsw;

    // staging decomposition: 4 lanes per 64B row-chunk, group XOR-swizzled
    const int srl = lane >> 2;                    // row/col within 16-group
    const int sg  = (lane & 3) ^ swz(srl);        // global 16B group to fetch

    unsigned L[2][TK];
#pragma unroll
    for (int h = 0; h < 2; ++h)
#pragma unroll
        for (int s = 0; s < TK; ++s) L[h][s] = 0xFFFFFFFFu;

    const int srow = tid >> 2;      // selection: 4 threads per score-row
    const int scp  = tid & 3;       // each scans 64 cols

    for (int ct = 0; ct < 8; ++ct) {
        const int colb = quarter * 2048 + ct * 256;

        float sqv[8];
#pragma unroll
        for (int cf = 0; cf < 8; ++cf) sqv[cf] = sqg[colb + wc * 128 + cf * 16 + l15];

        floatx4 acc[4][8];
#pragma unroll
        for (int rf = 0; rf < 4; ++rf)
#pragma unroll
            for (int cf = 0; cf < 8; ++cf) acc[rf][cf] = (floatx4)0.f;

        for (int kt = 0; kt < 16; ++kt) {
            const int kb = kt * 32;
            __syncthreads();
#pragma unroll
            for (int p = 0; p < 2; ++p) {
                int rg = wid * 2 + p;
                gl_lds16(bfb + (size_t)(row0 + rg * 16 + srl) * FDIM + kb + sg * 8,
                         &As[rg * 512]);
            }
#pragma unroll
            for (int p = 0; p < 4; ++p) {
                int cg = wid * 4 + p;
                gl_lds16(bfb + (size_t)(colb + cg * 16 + srl) * FDIM + kb + sg * 8,
                         &Bs[cg * 512]);
            }
            __syncthreads();

            short8 av[4], bv[8];
#pragma unroll
            for (int rf = 0; rf < 4; ++rf) av[rf] = *(const short8*)&As[aoff[rf]];
#pragma unroll
            for (int cf = 0; cf < 8; ++cf) bv[cf] = *(const short8*)&Bs[boff[cf]];
#pragma unroll
            for (int rf = 0; rf < 4; ++rf)
#pragma unroll
                for (int cf = 0; cf < 8; ++cf)
                    acc[rf][cf] = __builtin_amdgcn_mfma_f32_16x16x32_bf16(
                        av[rf], bv[cf], acc[rf][cf], 0, 0, 0);
        }

        // epilogue: two 64-row phases (Sc buffer holds 64 rows)
#pragma unroll
        for (int hr = 0; hr < 2; ++hr) {
            __syncthreads();
            if (wr == hr) {
#pragma unroll
                for (int rf = 0; rf < 4; ++rf)
#pragma unroll
                    for (int cf = 0; cf < 8; ++cf) {
                        const int ctl = wc * 128 + cf * 16 + l15;
                        const int gcol = colb + ctl;
#pragma unroll
                        for (int v = 0; v < 4; ++v) {
                            const int rbuf = rf * 16 + q * 4 + v;
                            const int grow = row0 + hr * 64 + rbuf;
                            float s = fmaf(-32.f, acc[rf][cf][v], sqv[cf]);
                            s = fminf(fmaxf(s, 0.f), 65535.f);
                            ushort us = (grow == gcol) ? (ushort)65535 : (ushort)s;
                            Sc[rbuf * 264 + ctl] = us;
                        }
                    }
            }
            __syncthreads();
            const ushort* base = &Sc[srow * 264 + scp * 64];
            const int colg0 = colb + scp * 64;
            unsigned* Lp = L[hr];
#pragma unroll
            for (int j = 0; j < 8; ++j) {
                uint4 w = *(const uint4*)(base + j * 8);
                // fast-reject: min of the 8 packed u16 scores vs current 12th score.
                // skip is safe only when ALL scores are strictly greater (score==thr
                // could still win its col tie-break), hence <= enters the slow path.
                unsigned m = pkminu16(pkminu16(w.x, w.y), pkminu16(w.z, w.w));
                unsigned mm = min(m & 0xFFFFu, m >> 16);
                unsigned thr = Lp[TK - 1] >> 16;
                if (mm <= thr) {
                    const int c0 = colg0 + j * 8;
                    unsigned k;
                    k = (w.x << 16) | (unsigned)(c0 + 0); if (k < Lp[TK-1]) insert12(Lp, k);
                    k = (w.x & 0xFFFF0000u) | (unsigned)(c0 + 1); if (k < Lp[TK-1]) insert12(Lp, k);
                    k = (w.y << 16) | (unsigned)(c0 + 2); if (k < Lp[TK-1]) insert12(Lp, k);
                    k = (w.y & 0xFFFF0000u) | (unsigned)(c0 + 3); if (k < Lp[TK-1]) insert12(Lp, k);
                    k = (w.z << 16) | (unsigned)(c0 + 4); if (k < Lp[TK-1]) insert12(Lp, k);
                    k = (w.z & 0xFFFF0000u) | (unsigned)(c0 + 5); if (k < Lp[TK-1]) insert12(Lp, k);
                    k = (w.w << 16) | (unsigned)(c0 + 6); if (k < Lp[TK-1]) insert12(Lp, k);
                    k = (w.w & 0xFFFF0000u) | (unsigned)(c0 + 7); if (k < Lp[TK-1]) insert12(Lp, k);
                }
            }
        }
    }

    // merge the 4 scanners of each row (butterfly, snapshot-then-insert)
#pragma unroll
    for (int m = 1; m <= 2; m <<= 1) {
#pragma unroll
        for (int h = 0; h < 2; ++h) {
            unsigned o[TK];
#pragma unroll
            for (int s = 0; s < TK; ++s) o[s] = (unsigned)__shfl_xor((int)L[h][s], m);
#pragma unroll
            for (int s = 0; s < TK; ++s)
                if (o[s] < L[h][TK - 1]) insert12(L[h], o[s]);
        }
    }

    if (scp == 0) {
#pragma unroll
        for (int h = 0; h < 2; ++h) {
            const int grow = row0 + h * 64 + srow;
            unsigned* dst = cand + ((size_t)(b * NQ + quarter) * NPTS + grow) * TK;
#pragma unroll
            for (int s = 0; s < TK; ++s) dst[s] = L[h][s];   // full 32-bit keys
        }
    }
}

// ---------------- merge 4x12 keys -> top-12, fp64 exact re-rank, adjacency scatter
__global__ void refine_kernel(const float* __restrict__ feats, const unsigned* __restrict__ cand,
                              float* __restrict__ adj) {
    __shared__ unsigned scols[4][TK];
    const int wv   = threadIdx.x >> 6;
    const int lane = threadIdx.x & 63;
    const int gw = blockIdx.x * 4 + wv;             // 0..16383
    const int b = gw >> 13;
    const int r = gw & (NPTS - 1);

    // load the 4 quarter-lists (48 keys; scores globally comparable, cols unique)
    unsigned key = 0xFFFFFFFFu;
    if (lane < NQ * TK) {
        int qf = lane / TK, s = lane % TK;
        key = cand[((size_t)(b * NQ + qf) * NPTS + r) * TK + s];
    }
    int rank = 0;
#pragma unroll
    for (int u = 0; u < NQ * TK; ++u) {
        unsigned ku = (unsigned)__shfl((int)key, u);
        rank += (ku < key) ? 1 : 0;
    }
    if (lane < NQ * TK && rank < TK) scols[wv][rank] = key & 0xFFFFu;
    __syncthreads();

    const float* fb = feats + (size_t)b * NPTS * FDIM;
    const float* fr = fb + (size_t)r * FDIM + lane * 8;
    float* adjb = adj + (size_t)b * NPTS * NPTS;

    float4 a0 = *(const float4*)fr;
    float4 a1 = *(const float4*)(fr + 4);

    double dist[TK];
#pragma unroll
    for (int t = 0; t < TK; ++t) {
        int c = (int)scols[wv][t];
        const float* fc = fb + (size_t)c * FDIM + lane * 8;
        float4 c0 = *(const float4*)fc;
        float4 c1 = *(const float4*)(fc + 4);
        double sm = 0.0, e;
        e = (double)a0.x - (double)c0.x; sm += e * e;
        e = (double)a0.y - (double)c0.y; sm += e * e;
        e = (double)a0.z - (double)c0.z; sm += e * e;
        e = (double)a0.w - (double)c0.w; sm += e * e;
        e = (double)a1.x - (double)c1.x; sm += e * e;
        e = (double)a1.y - (double)c1.y; sm += e * e;
        e = (double)a1.z - (double)c1.z; sm += e * e;
        e = (double)a1.w - (double)c1.w; sm += e * e;
#pragma unroll
        for (int off = 32; off > 0; off >>= 1) sm += __shfl_xor(sm, off);
        dist[t] = sm;
    }

    if (lane < TK) {
        const int t = lane;
        const int ct = (int)scols[wv][t];
        int rk = 0;
#pragma unroll
        for (int u = 0; u < TK; ++u) {
            int cu = (int)scols[wv][u];
            rk += (dist[u] < dist[t]) || (dist[u] == dist[t] && cu < ct);
        }
        if (rk < KNN) {
            atomicAdd(&adjb[(size_t)r * NPTS + ct], 0.5f);
            atomicAdd(&adjb[(size_t)ct * NPTS + r], 0.5f);
        }
    }
}

extern "C" void kernel_launch(void* const* d_in, const int* in_sizes, int n_in,
                              void* d_out, int out_size, void* d_ws, size_t ws_size,
                              hipStream_t stream) {
    (void)in_sizes; (void)n_in; (void)out_size; (void)ws_size;
    const float* img = (const float*)d_in[0];

    float* feats = (float*)d_out;                               // 2*8192*512
    float* adj   = feats + (size_t)NB * NPTS * FDIM;            // 2*8192*8192

    float*    sqc16 = (float*)d_ws;                             // 16384 floats
    unsigned* cand  = (unsigned*)((char*)d_ws + 65536);         // 16384*4*12 u32 (~3.1 MB)
    ushort*   bfeat = (ushort*)adj;  // bf16 feats staged in adj region (wiped by memset later)

    extract_prep_kernel<<<8192, 256, 0, stream>>>(img, feats, bfeat, sqc16);
    knn_mfma      <<<dim3(NPTS / 128, NB, NQ), 256, 0, stream>>>(bfeat, sqc16, cand);
    (void)hipMemsetAsync(adj, 0, (size_t)NB * NPTS * NPTS * sizeof(float), stream);
    refine_kernel <<<(NB * NPTS) / 4, 256, 0, stream>>>(feats, cand, adj);
}